// Round 9
// baseline (2538.808 us; speedup 1.0000x reference)
//
#include <hip/hip_runtime.h>
#include <hip/hip_bf16.h>

typedef unsigned short ushort_t;
typedef short short8 __attribute__((ext_vector_type(8)));
typedef float floatx4 __attribute__((ext_vector_type(4)));

#define FEAT 128
#define HF   512
#define NRBF 50
#define NNODE 10000
#define NEDGE 250000

__device__ __forceinline__ float b2f(unsigned int b){
    unsigned int u = (b & 0xffffu) << 16;
    float f; __builtin_memcpy(&f, &u, 4); return f;
}
__device__ __forceinline__ unsigned short f2b(float f){
    __hip_bfloat16 h = __float2bfloat16(f);
    unsigned short u; __builtin_memcpy(&u, &h, 2); return u;
}
__device__ __forceinline__ float silu_f(float x){ return x / (1.f + __expf(-x)); }

// fp32 inputs iff low 16 bits of ln_gamma[0] are zero (R4/R7: fp32 confirmed on HW)
__device__ __forceinline__ bool is_fp32(const void* lng){
    return ((((const unsigned int*)lng)[0]) & 0xffffu) == 0u;
}
__device__ __forceinline__ float ld_f(const void* p, long idx, bool fp32){
    return fp32 ? ((const float*)p)[idx] : b2f(((const ushort_t*)p)[idx]);
}
__device__ __forceinline__ ushort_t ld_bf(const void* p, long idx, bool fp32){
    return fp32 ? f2b(((const float*)p)[idx]) : ((const ushort_t*)p)[idx];
}

// ---------------- sentinel (ws too small; should never fire) --------------------------
__global__ __launch_bounds__(256) void k_sentinel(float* __restrict__ out){
    int x = blockIdx.x*256 + threadIdx.x;
    if (x < NNODE*FEAT*4) out[x] = 1.0f;
}

// ---------------- normalize nbrs (int32 or int64) -> clamped int32 --------------------
__global__ __launch_bounds__(256) void k_nbrs(const unsigned int* __restrict__ raw, int* __restrict__ out){
    int x = blockIdx.x*256 + threadIdx.x;
    if (x >= 2*NEDGE) return;
    unsigned int m = raw[1]|raw[3]|raw[5]|raw[7]|raw[9]|raw[11]|raw[13]|raw[15];
    int v = (m == 0u) ? (int)raw[2*x] : (int)raw[x];
    out[x] = ((unsigned)v < (unsigned)NNODE) ? v : 0;
}

// ---------------- counting sort of edges by destination i -----------------------------
__global__ __launch_bounds__(256) void k_count(const int* __restrict__ nb32, int* __restrict__ cnt){
    int x = blockIdx.x*256 + threadIdx.x;
    if (x >= NEDGE) return;
    atomicAdd(&cnt[nb32[2*x]], 1);
}
__global__ __launch_bounds__(256) void k_scan(const int* __restrict__ cnt, int* __restrict__ cursor){
    __shared__ int part[256];
    __shared__ int base[256];
    const int t = threadIdx.x;
    const int start = t*40;                 // 256*40 = 10240 >= 10000
    int s = 0;
    for (int u=0; u<40; u++){ int idx = start+u; if (idx < NNODE) s += cnt[idx]; }
    part[t] = s;
    __syncthreads();
    if (t == 0){
        int run = 0;
        for (int u=0; u<256; u++){ base[u] = run; run += part[u]; }
    }
    __syncthreads();
    int run = base[t];
    for (int u=0; u<40; u++){
        int idx = start+u;
        if (idx < NNODE){ cursor[idx] = run; run += cnt[idx]; }
    }
}
__global__ __launch_bounds__(256) void k_place(const int* __restrict__ nb32,
                                               int* __restrict__ cursor, int* __restrict__ perm){
    int x = blockIdx.x*256 + threadIdx.x;
    if (x >= NEDGE) return;
    int i = nb32[2*x];
    int pos = atomicAdd(&cursor[i], 1);
    perm[pos] = x;
}

// ---------------- canonicalize ln/biases -> bf16 block --------------------------------
// cb (ushort): ln_g@0(128) ln_b@128(128) bq@256 bk@768 bv@1280 bdk@1792 bdv@2304 bd@2816(384)
__global__ __launch_bounds__(256) void k_conv(
    const void* ln_g, const void* ln_b, const void* bq, const void* bk, const void* bv,
    const void* bdk, const void* bdv, const void* bd, ushort_t* __restrict__ cb)
{
    const int t = threadIdx.x;
    const bool fp32 = is_fp32(ln_g);
    const void* srcs[8] = {ln_g, ln_b, bq, bk, bv, bdk, bdv, bd};
    const int offs[9] = {0,128,256,768,1280,1792,2304,2816,3200};
    for (int s=0; s<8; s++){
        int cnt = offs[s+1]-offs[s];
        for (int x=t; x<cnt; x+=256) cb[offs[s]+x] = ld_bf(srcs[s], x, fp32);
    }
}

// ---------------- weight transposes into B-fragment layouts ---------------------------
// WqT/WkT/WvT: [512][128]; WdkT/WdvT: [512][64] (k zero-padded 50..63); WdT: [384][512]
__global__ __launch_bounds__(256) void k_prep(
    const void* __restrict__ Wq, const void* __restrict__ Wk, const void* __restrict__ Wv,
    const void* __restrict__ Wdk, const void* __restrict__ Wdv, const void* __restrict__ Wd,
    const void* __restrict__ lng,
    ushort_t* __restrict__ WqT, ushort_t* __restrict__ WkT, ushort_t* __restrict__ WvT,
    ushort_t* __restrict__ WdkT, ushort_t* __restrict__ WdvT, ushort_t* __restrict__ WdT)
{
    const bool fp32 = is_fp32(lng);
    int idx = blockIdx.x*256 + threadIdx.x;
    if (idx < 3*65536){
        int mat = idx >> 16; int o = idx & 65535;
        int c = o >> 7, r = o & 127;
        const void* src = (mat==0)?Wq:((mat==1)?Wk:Wv);
        ushort_t* dst = (mat==0)?WqT:((mat==1)?WkT:WvT);
        dst[o] = ld_bf(src, r*HF + c, fp32);
    } else if (idx < 3*65536 + 2*32768){
        int o2 = idx - 3*65536; int mat = o2 >> 15; int o = o2 & 32767;
        int c = o >> 6, kk = o & 63;
        const void* src = mat ? Wdv : Wdk;
        ushort_t* dst = mat ? WdvT : WdkT;
        dst[o] = (kk < NRBF) ? ld_bf(src, kk*HF + c, fp32) : (ushort_t)0;
    } else {
        int o = idx - (3*65536 + 2*32768);
        int c = o >> 9, kk = o & 511;
        WdT[o] = ld_bf(Wd, kk*384 + c, fp32);
    }
}

// ---------------- K1: LayerNorm + QKV projections (MFMA, 16 nodes/block) --------------
__global__ __launch_bounds__(256) void k_qkv2(
    const void* __restrict__ s_j, const void* __restrict__ lng, const ushort_t* __restrict__ cb,
    const ushort_t* __restrict__ WqT, const ushort_t* __restrict__ WkT, const ushort_t* __restrict__ WvT,
    ushort_t* __restrict__ q, ushort_t* __restrict__ k, ushort_t* __restrict__ v)
{
    __shared__ __align__(16) ushort_t xlds[16][136];   // row stride 272B = 17*16
    const int t = threadIdx.x;
    const int n = t >> 4, g = t & 15;
    const long node = (long)blockIdx.x*16 + n;
    const bool fp32 = is_fp32(lng);

    float xs[8];
    if (fp32){
        const float* sf = (const float*)s_j + node*FEAT + g*8;
        #pragma unroll
        for (int i=0;i<8;i++) xs[i] = sf[i];
    } else {
        short8 sv = *reinterpret_cast<const short8*>((const ushort_t*)s_j + node*FEAT + g*8);
        #pragma unroll
        for (int i=0;i<8;i++) xs[i] = b2f((unsigned short)sv[i]);
    }
    float sum = 0.f, ss = 0.f;
    #pragma unroll
    for (int i=0;i<8;i++){ sum += xs[i]; ss += xs[i]*xs[i]; }
    #pragma unroll
    for (int off=8; off; off>>=1){ sum += __shfl_xor(sum, off, 16); ss += __shfl_xor(ss, off, 16); }
    float mu = sum * (1.f/FEAT);
    float var = ss * (1.f/FEAT) - mu*mu;       // population var (jnp.var)
    float sc = rsqrtf(var + 1e-5f);
    short8 gv  = *reinterpret_cast<const short8*>(cb + g*8);
    short8 bv2 = *reinterpret_cast<const short8*>(cb + 128 + g*8);
    short8 xv;
    #pragma unroll
    for (int i=0;i<8;i++){
        float val = (xs[i]-mu)*sc*b2f((unsigned short)gv[i]) + b2f((unsigned short)bv2[i]);
        xv[i] = (short)f2b(val);
    }
    *reinterpret_cast<short8*>(&xlds[n][g*8]) = xv;
    __syncthreads();

    const int lane = t & 63, w = t >> 6;
    const int col = lane & 15, quad = lane >> 4;
    short8 a[4];
    #pragma unroll
    for (int ks=0; ks<4; ks++)
        a[ks] = *reinterpret_cast<const short8*>(&xlds[col][ks*32 + quad*8]);

    for (int ii=0; ii<24; ii++){
        int nt = w + ii*4;
        int mat = nt >> 5, o0 = (nt & 31) << 4;
        const ushort_t* WT  = (mat==0)?WqT:((mat==1)?WkT:WvT);
        const ushort_t* bia = cb + 256 + mat*512;
        ushort_t* outp      = (mat==0)?q:((mat==1)?k:v);
        floatx4 acc = {0.f,0.f,0.f,0.f};
        #pragma unroll
        for (int ks=0; ks<4; ks++){
            short8 b = *reinterpret_cast<const short8*>(WT + (o0+col)*FEAT + ks*32 + quad*8);
            acc = __builtin_amdgcn_mfma_f32_16x16x32_bf16(a[ks], b, acc, 0, 0, 0);
        }
        float bc = b2f(bia[o0+col]);
        #pragma unroll
        for (int reg=0; reg<4; reg++){
            int row = quad*4 + reg;         // C/D: row=quad*4+reg, col=lane&15
            outp[((long)blockIdx.x*16 + row)*HF + o0 + col] = f2b(acc[reg] + bc);
        }
    }
}

// ---------------- K2: fused edge kernel (MFMA), 64 sorted edges/block, 4x16 chunks ----
struct __align__(16) EdgeSmem {
    int   i[16];
    int   jv[16];
    float unit[16][3];
    float dist[16];
    float attn[16][4];
    ushort_t rbf[16][72];           // row stride 144B
    union {
        ushort_t dkdv[2][16][520];  // row stride 1040B; dead after P4
        float    outb[16*385];      // overlay for P5/P6
    };
    ushort_t msg[16][520];          // row stride 1040B
};

__global__ __launch_bounds__(256) void k_edge(
    const void* __restrict__ r_ij, const void* __restrict__ lng,
    const int* __restrict__ nbrs32, const int* __restrict__ perm,
    const ushort_t* __restrict__ q, const ushort_t* __restrict__ k, const ushort_t* __restrict__ v,
    const void* __restrict__ v_j,
    const ushort_t* __restrict__ WdkT, const ushort_t* __restrict__ WdvT,
    const ushort_t* __restrict__ cb,
    const ushort_t* __restrict__ WdT,
    float* __restrict__ acc_s, float* __restrict__ acc_v)
{
    __shared__ EdgeSmem sm;
    const int t = threadIdx.x;
    const bool fp32 = is_fp32(lng);
    const int lane = t & 63, w = t >> 6;
    const int col = lane & 15, quad = lane >> 4;

    // run-accumulator state for the scatter walkers (t < 128, f = t)
    int   cur_i = -1;
    float as = 0.f, av0 = 0.f, av1 = 0.f, av2 = 0.f;

    for (int c = 0; c < 4; c++){
        const long ce0 = ((long)blockIdx.x*4 + c) * 16;
        if (ce0 >= NEDGE) break;              // block-uniform; NEDGE%16==0 => chunks all-real

        // P1: dist / unit / indices via perm (sorted by destination i)
        if (t < 16){
            int e = t;
            int ep = perm[ce0 + e];
            float rx = ld_f(r_ij, (long)ep*3+0, fp32);
            float ry = ld_f(r_ij, (long)ep*3+1, fp32);
            float rz = ld_f(r_ij, (long)ep*3+2, fp32);
            float d = sqrtf(rx*rx + ry*ry + rz*rz + 3e-15f);
            sm.dist[e] = d;
            float inv = 1.f/d;
            sm.unit[e][0] = rx*inv; sm.unit[e][1] = ry*inv; sm.unit[e][2] = rz*inv;
            sm.i[e]  = nbrs32[2*ep];
            sm.jv[e] = nbrs32[2*ep+1];
        }
        __syncthreads();
        // P1b: rbf (bf16, zero-padded to k=64)
        {
            const float WIDTH = 5.f/49.f;
            const float GAMMA = 0.5f/(WIDTH*WIDTH);
            int e = t & 15, m0 = t >> 4;
            float d = sm.dist[e];
            for (int m = m0; m < 64; m += 16){
                float val = 0.f;
                if (m < NRBF){ float dm = d - (float)m*WIDTH; val = __expf(-GAMMA*dm*dm); }
                sm.rbf[e][m] = f2b(val);
            }
        }
        __syncthreads();

        // P2: dk/dv = silu(rbf @ Wdk/Wdv + b) via MFMA (K=64 -> 2 steps)
        {
            short8 a0 = *reinterpret_cast<const short8*>(&sm.rbf[col][quad*8]);
            short8 a1 = *reinterpret_cast<const short8*>(&sm.rbf[col][32 + quad*8]);
            for (int ii=0; ii<16; ii++){
                int nt = w + ii*4;
                int mat = nt >> 5, o0 = (nt & 31) << 4;
                const ushort_t* WT  = mat ? WdvT : WdkT;
                const ushort_t* bia = cb + 1792 + mat*512;
                floatx4 acc = {0.f,0.f,0.f,0.f};
                short8 b0 = *reinterpret_cast<const short8*>(WT + (o0+col)*64 + quad*8);
                acc = __builtin_amdgcn_mfma_f32_16x16x32_bf16(a0, b0, acc, 0, 0, 0);
                short8 b1 = *reinterpret_cast<const short8*>(WT + (o0+col)*64 + 32 + quad*8);
                acc = __builtin_amdgcn_mfma_f32_16x16x32_bf16(a1, b1, acc, 0, 0, 0);
                float bc = b2f(bia[o0+col]);
                #pragma unroll
                for (int reg=0; reg<4; reg++){
                    int row = quad*4 + reg;
                    sm.dkdv[mat][row][o0+col] = f2b(silu_f(acc[reg] + bc));
                }
            }
        }
        __syncthreads();

        // P3: attn[e][h] = silu( sum_f q[i,h,f]*k[j,h,f]*dk[e,h,f] ); wave w = head w
        {
            int f = w*128 + 2*lane;
            for (int e=0; e<16; e++){
                long i = sm.i[e], jj = sm.jv[e];
                unsigned int qb = *reinterpret_cast<const unsigned int*>(q + i*HF + f);
                unsigned int kb = *reinterpret_cast<const unsigned int*>(k + jj*HF + f);
                unsigned int db = *reinterpret_cast<const unsigned int*>(&sm.dkdv[0][e][f]);
                float p = b2f(qb)*b2f(kb)*b2f(db) + b2f(qb>>16)*b2f(kb>>16)*b2f(db>>16);
                #pragma unroll
                for (int off=32; off; off>>=1) p += __shfl_xor(p, off, 64);
                if (lane == 0) sm.attn[e][w] = silu_f(p);
            }
        }
        __syncthreads();

        // P4: msg[e][f] = v[j,f] * dv[e,f] * attn[e][f/128]
        {
            int f = 2*t;
            int h = t >> 6;
            for (int e=0; e<16; e++){
                long jj = sm.jv[e];
                float at = sm.attn[e][h];
                unsigned int vb = *reinterpret_cast<const unsigned int*>(v + jj*HF + f);
                unsigned int db = *reinterpret_cast<const unsigned int*>(&sm.dkdv[1][e][f]);
                float m0v = b2f(vb)*b2f(db)*at;
                float m1v = b2f(vb>>16)*b2f(db>>16)*at;
                unsigned int o = (unsigned int)f2b(m0v) | ((unsigned int)f2b(m1v) << 16);
                *reinterpret_cast<unsigned int*>(&sm.msg[e][f]) = o;
            }
        }
        __syncthreads();

        // P5: out = msg(16x512) @ Wd(512x384) + bd via MFMA; out overlays dk/dv (dead)
        {
            floatx4 acc[6];
            #pragma unroll
            for (int ii=0; ii<6; ii++) acc[ii] = (floatx4){0.f,0.f,0.f,0.f};
            for (int ks=0; ks<16; ks++){
                short8 a = *reinterpret_cast<const short8*>(&sm.msg[col][ks*32 + quad*8]);
                #pragma unroll
                for (int ii=0; ii<6; ii++){
                    int o0 = (w + ii*4) << 4;
                    short8 b = *reinterpret_cast<const short8*>(WdT + (o0+col)*HF + ks*32 + quad*8);
                    acc[ii] = __builtin_amdgcn_mfma_f32_16x16x32_bf16(a, b, acc[ii], 0, 0, 0);
                }
            }
            #pragma unroll
            for (int ii=0; ii<6; ii++){
                int o0 = (w + ii*4) << 4;
                float bc = b2f(cb[2816 + o0 + col]);
                #pragma unroll
                for (int reg=0; reg<4; reg++){
                    int row = quad*4 + reg;
                    sm.outb[row*385 + o0 + col] = acc[ii][reg] + bc;
                }
            }
        }
        __syncthreads();

        // P6: run-aggregated scatter (sorted by i => flush only on destination change)
        if (t < 128){
            const int f = t;
            for (int e = 0; e < 16; e++){
                int ie = sm.i[e];
                if (ie != cur_i){                       // wave-uniform branch (same e,i for all f)
                    if (cur_i >= 0){
                        atomicAdd(&acc_s[(long)cur_i*FEAT + f], as);
                        float* ap = acc_v + ((long)cur_i*FEAT + f)*3;
                        atomicAdd(ap+0, av0); atomicAdd(ap+1, av1); atomicAdd(ap+2, av2);
                    }
                    cur_i = ie; as = 0.f; av0 = 0.f; av1 = 0.f; av2 = 0.f;
                }
                float o0v = sm.outb[e*385 + f];
                float o1v = sm.outb[e*385 + 128 + f];
                float o2v = sm.outb[e*385 + 256 + f];
                long base = ((long)sm.jv[e]*FEAT + f)*3;
                float vj0 = ld_f(v_j, base+0, fp32);
                float vj1 = ld_f(v_j, base+1, fp32);
                float vj2 = ld_f(v_j, base+2, fp32);
                as  += o1v;
                av0 += o2v*sm.unit[e][0] + o0v*vj0;
                av1 += o2v*sm.unit[e][1] + o0v*vj1;
                av2 += o2v*sm.unit[e][2] + o0v*vj2;
            }
        }
        __syncthreads();   // walkers done before next chunk overwrites LDS
    }

    // final flush
    if (t < 128 && cur_i >= 0){
        const int f = t;
        atomicAdd(&acc_s[(long)cur_i*FEAT + f], as);
        float* ap = acc_v + ((long)cur_i*FEAT + f)*3;
        atomicAdd(ap+0, av0); atomicAdd(ap+1, av1); atomicAdd(ap+2, av2);
    }
}

// ---------------- fp32 accumulators -> fp32 output ----------------
__global__ __launch_bounds__(256) void k_out(const float* __restrict__ acc, float* __restrict__ out){
    int idx = blockIdx.x*256 + threadIdx.x;
    out[idx] = acc[idx];
}

extern "C" void kernel_launch(void* const* d_in, const int* in_sizes, int n_in,
                              void* d_out, int out_size, void* d_ws, size_t ws_size,
                              hipStream_t stream)
{
    const void* s_j  = d_in[0];
    const void* v_j  = d_in[1];
    const void* r_ij = d_in[2];
    const unsigned int* nbrs_raw = (const unsigned int*)d_in[3];
    const void* ln_g = d_in[4];
    const void* ln_b = d_in[5];
    const void* Wq = d_in[6];   const void* bq  = d_in[7];
    const void* Wk = d_in[8];   const void* bk  = d_in[9];
    const void* Wv = d_in[10];  const void* bv  = d_in[11];
    const void* Wdk= d_in[12];  const void* bdk = d_in[13];
    const void* Wdv= d_in[14];  const void* bdv = d_in[15];
    const void* Wd = d_in[16];  const void* bd  = d_in[17];

    // ws layout (bytes) — identical to R8 (proven size):
    //   acc 0..20,480,000 | kk 20,480,000 | vv 30,720,000 | WqT 40,960,000 (+131072) WkT WvT
    //   WdkT 41,353,216 (+65536) WdvT | WdT 41,484,288 (+393216) | nbrs32 41,877,504 (+2,000,000)
    //   cb 43,877,504 (+6,400) => NEED 43,883,904
    const size_t NEED = 43883904;
    if (ws_size < NEED){
        k_sentinel<<<20000, 256, 0, stream>>>((float*)d_out);
        return;
    }

    char* ws = (char*)d_ws;
    float*    acc  = (float*)(ws);
    ushort_t* kk   = (ushort_t*)(ws + 20480000);
    ushort_t* vv   = (ushort_t*)(ws + 30720000);
    ushort_t* WqT  = (ushort_t*)(ws + 40960000);
    ushort_t* WkT  = (ushort_t*)(ws + 41091072);
    ushort_t* WvT  = (ushort_t*)(ws + 41222144);
    ushort_t* WdkT = (ushort_t*)(ws + 41353216);
    ushort_t* WdvT = (ushort_t*)(ws + 41418752);
    ushort_t* WdT  = (ushort_t*)(ws + 41484288);
    int*      nb32 = (int*)(ws + 41877504);
    ushort_t* cb   = (ushort_t*)(ws + 43877504);

    // d_out (20.48 MB fp32) doubles as scratch until k_out:
    //   [0,10.24MB) q staging (bf16) | perm @10,240,000 (1MB) | cnt @11,240,000 | cursor @11,280,000
    char* dob = (char*)d_out;
    ushort_t* q    = (ushort_t*)dob;
    int*      perm = (int*)(dob + 10240000);
    int*      cnt  = (int*)(dob + 11240000);
    int*      curs = (int*)(dob + 11280000);

    hipMemsetAsync(acc, 0, 20480000, stream);
    hipMemsetAsync(cnt, 0, NNODE*sizeof(int), stream);
    k_nbrs <<<1954, 256, 0, stream>>>(nbrs_raw, nb32);
    k_count<<<977, 256, 0, stream>>>(nb32, cnt);
    k_scan <<<1, 256, 0, stream>>>(cnt, curs);
    k_place<<<977, 256, 0, stream>>>(nb32, curs, perm);
    k_conv <<<1, 256, 0, stream>>>(ln_g, ln_b, bq, bk, bv, bdk, bdv, bd, cb);
    k_prep <<<1792, 256, 0, stream>>>(Wq,Wk,Wv,Wdk,Wdv,Wd, ln_g, WqT,WkT,WvT,WdkT,WdvT,WdT);
    k_qkv2 <<<625, 256, 0, stream>>>(s_j, ln_g, cb, WqT, WkT, WvT, q, kk, vv);
    k_edge <<<3907, 256, 0, stream>>>(r_ij, ln_g, nb32, perm, q, kk, vv, v_j,
                                      WdkT, WdvT, cb, WdT,
                                      acc, acc + 1280000);
    k_out  <<<20000, 256, 0, stream>>>(acc, (float*)d_out);
}

// Round 10
// 1243.864 us; speedup vs baseline: 2.0411x; 2.0411x over previous
//
#include <hip/hip_runtime.h>
#include <hip/hip_bf16.h>

typedef unsigned short ushort_t;
typedef short short8 __attribute__((ext_vector_type(8)));
typedef short short4v __attribute__((ext_vector_type(4)));
typedef float floatx4 __attribute__((ext_vector_type(4)));

#define FEAT 128
#define HF   512
#define NRBF 50
#define NNODE 10000
#define NEDGE 250000

__device__ __forceinline__ float b2f(unsigned int b){
    unsigned int u = (b & 0xffffu) << 16;
    float f; __builtin_memcpy(&f, &u, 4); return f;
}
__device__ __forceinline__ unsigned short f2b(float f){
    __hip_bfloat16 h = __float2bfloat16(f);
    unsigned short u; __builtin_memcpy(&u, &h, 2); return u;
}
__device__ __forceinline__ float silu_f(float x){ return x / (1.f + __expf(-x)); }

// fp32 inputs iff low 16 bits of ln_gamma[0] are zero (R4/R7: fp32 confirmed on HW)
__device__ __forceinline__ bool is_fp32(const void* lng){
    return ((((const unsigned int*)lng)[0]) & 0xffffu) == 0u;
}
__device__ __forceinline__ float ld_f(const void* p, long idx, bool fp32){
    return fp32 ? ((const float*)p)[idx] : b2f(((const ushort_t*)p)[idx]);
}
__device__ __forceinline__ ushort_t ld_bf(const void* p, long idx, bool fp32){
    return fp32 ? f2b(((const float*)p)[idx]) : ((const ushort_t*)p)[idx];
}

// ---------------- sentinel (ws too small; should never fire) --------------------------
__global__ __launch_bounds__(256) void k_sentinel(float* __restrict__ out){
    int x = blockIdx.x*256 + threadIdx.x;
    if (x < NNODE*FEAT*4) out[x] = 1.0f;
}

// ---------------- normalize nbrs (int32 or int64) -> clamped int32 --------------------
__global__ __launch_bounds__(256) void k_nbrs(const unsigned int* __restrict__ raw, int* __restrict__ out){
    int x = blockIdx.x*256 + threadIdx.x;
    if (x >= 2*NEDGE) return;
    unsigned int m = raw[1]|raw[3]|raw[5]|raw[7]|raw[9]|raw[11]|raw[13]|raw[15];
    int v = (m == 0u) ? (int)raw[2*x] : (int)raw[x];
    out[x] = ((unsigned)v < (unsigned)NNODE) ? v : 0;
}

// ---------------- counting sort of edges by destination i (validated R9) --------------
__global__ __launch_bounds__(256) void k_count(const int* __restrict__ nb32, int* __restrict__ cnt){
    int x = blockIdx.x*256 + threadIdx.x;
    if (x >= NEDGE) return;
    atomicAdd(&cnt[nb32[2*x]], 1);
}
__global__ __launch_bounds__(256) void k_scan(const int* __restrict__ cnt, int* __restrict__ cursor){
    __shared__ int part[256];
    __shared__ int base[256];
    const int t = threadIdx.x;
    const int start = t*40;                 // 256*40 = 10240 >= 10000
    int s = 0;
    for (int u=0; u<40; u++){ int idx = start+u; if (idx < NNODE) s += cnt[idx]; }
    part[t] = s;
    __syncthreads();
    if (t == 0){
        int run = 0;
        for (int u=0; u<256; u++){ base[u] = run; run += part[u]; }
    }
    __syncthreads();
    int run = base[t];
    for (int u=0; u<40; u++){
        int idx = start+u;
        if (idx < NNODE){ cursor[idx] = run; run += cnt[idx]; }
    }
}
__global__ __launch_bounds__(256) void k_place(const int* __restrict__ nb32,
                                               int* __restrict__ cursor, int* __restrict__ perm){
    int x = blockIdx.x*256 + threadIdx.x;
    if (x >= NEDGE) return;
    int i = nb32[2*x];
    int pos = atomicAdd(&cursor[i], 1);
    perm[pos] = x;
}

// ---------------- canonicalize ln/biases -> bf16 block --------------------------------
// cb (ushort): ln_g@0(128) ln_b@128(128) bq@256 bk@768 bv@1280 bdk@1792 bdv@2304 bd@2816(384)
__global__ __launch_bounds__(256) void k_conv(
    const void* ln_g, const void* ln_b, const void* bq, const void* bk, const void* bv,
    const void* bdk, const void* bdv, const void* bd, ushort_t* __restrict__ cb)
{
    const int t = threadIdx.x;
    const bool fp32 = is_fp32(ln_g);
    const void* srcs[8] = {ln_g, ln_b, bq, bk, bv, bdk, bdv, bd};
    const int offs[9] = {0,128,256,768,1280,1792,2304,2816,3200};
    for (int s=0; s<8; s++){
        int cnt = offs[s+1]-offs[s];
        for (int x=t; x<cnt; x+=256) cb[offs[s]+x] = ld_bf(srcs[s], x, fp32);
    }
}

// ---------------- weight transposes into B-fragment layouts ---------------------------
// WqT/WkT/WvT: [512][128]; WdkT/WdvT: [512][64] (k zero-padded 50..63); WdT: [384][512]
__global__ __launch_bounds__(256) void k_prep(
    const void* __restrict__ Wq, const void* __restrict__ Wk, const void* __restrict__ Wv,
    const void* __restrict__ Wdk, const void* __restrict__ Wdv, const void* __restrict__ Wd,
    const void* __restrict__ lng,
    ushort_t* __restrict__ WqT, ushort_t* __restrict__ WkT, ushort_t* __restrict__ WvT,
    ushort_t* __restrict__ WdkT, ushort_t* __restrict__ WdvT, ushort_t* __restrict__ WdT)
{
    const bool fp32 = is_fp32(lng);
    int idx = blockIdx.x*256 + threadIdx.x;
    if (idx < 3*65536){
        int mat = idx >> 16; int o = idx & 65535;
        int c = o >> 7, r = o & 127;
        const void* src = (mat==0)?Wq:((mat==1)?Wk:Wv);
        ushort_t* dst = (mat==0)?WqT:((mat==1)?WkT:WvT);
        dst[o] = ld_bf(src, r*HF + c, fp32);
    } else if (idx < 3*65536 + 2*32768){
        int o2 = idx - 3*65536; int mat = o2 >> 15; int o = o2 & 32767;
        int c = o >> 6, kk = o & 63;
        const void* src = mat ? Wdv : Wdk;
        ushort_t* dst = mat ? WdvT : WdkT;
        dst[o] = (kk < NRBF) ? ld_bf(src, kk*HF + c, fp32) : (ushort_t)0;
    } else {
        int o = idx - (3*65536 + 2*32768);
        int c = o >> 9, kk = o & 511;
        WdT[o] = ld_bf(Wd, kk*384 + c, fp32);
    }
}

// ---------------- K1: LayerNorm + QKV projections (MFMA, 16 nodes/block) --------------
__global__ __launch_bounds__(256) void k_qkv2(
    const void* __restrict__ s_j, const void* __restrict__ lng, const ushort_t* __restrict__ cb,
    const ushort_t* __restrict__ WqT, const ushort_t* __restrict__ WkT, const ushort_t* __restrict__ WvT,
    ushort_t* __restrict__ q, ushort_t* __restrict__ k, ushort_t* __restrict__ v)
{
    __shared__ __align__(16) ushort_t xlds[16][136];   // row stride 272B = 17*16
    const int t = threadIdx.x;
    const int n = t >> 4, g = t & 15;
    const long node = (long)blockIdx.x*16 + n;
    const bool fp32 = is_fp32(lng);

    float xs[8];
    if (fp32){
        const float* sf = (const float*)s_j + node*FEAT + g*8;
        #pragma unroll
        for (int i=0;i<8;i++) xs[i] = sf[i];
    } else {
        short8 sv = *reinterpret_cast<const short8*>((const ushort_t*)s_j + node*FEAT + g*8);
        #pragma unroll
        for (int i=0;i<8;i++) xs[i] = b2f((unsigned short)sv[i]);
    }
    float sum = 0.f, ss = 0.f;
    #pragma unroll
    for (int i=0;i<8;i++){ sum += xs[i]; ss += xs[i]*xs[i]; }
    #pragma unroll
    for (int off=8; off; off>>=1){ sum += __shfl_xor(sum, off, 16); ss += __shfl_xor(ss, off, 16); }
    float mu = sum * (1.f/FEAT);
    float var = ss * (1.f/FEAT) - mu*mu;       // population var (jnp.var)
    float sc = rsqrtf(var + 1e-5f);
    short8 gv  = *reinterpret_cast<const short8*>(cb + g*8);
    short8 bv2 = *reinterpret_cast<const short8*>(cb + 128 + g*8);
    short8 xv;
    #pragma unroll
    for (int i=0;i<8;i++){
        float val = (xs[i]-mu)*sc*b2f((unsigned short)gv[i]) + b2f((unsigned short)bv2[i]);
        xv[i] = (short)f2b(val);
    }
    *reinterpret_cast<short8*>(&xlds[n][g*8]) = xv;
    __syncthreads();

    const int lane = t & 63, w = t >> 6;
    const int col = lane & 15, quad = lane >> 4;
    short8 a[4];
    #pragma unroll
    for (int ks=0; ks<4; ks++)
        a[ks] = *reinterpret_cast<const short8*>(&xlds[col][ks*32 + quad*8]);

    for (int ii=0; ii<24; ii++){
        int nt = w + ii*4;
        int mat = nt >> 5, o0 = (nt & 31) << 4;
        const ushort_t* WT  = (mat==0)?WqT:((mat==1)?WkT:WvT);
        const ushort_t* bia = cb + 256 + mat*512;
        ushort_t* outp      = (mat==0)?q:((mat==1)?k:v);
        floatx4 acc = {0.f,0.f,0.f,0.f};
        #pragma unroll
        for (int ks=0; ks<4; ks++){
            short8 b = *reinterpret_cast<const short8*>(WT + (o0+col)*FEAT + ks*32 + quad*8);
            acc = __builtin_amdgcn_mfma_f32_16x16x32_bf16(a[ks], b, acc, 0, 0, 0);
        }
        float bc = b2f(bia[o0+col]);
        #pragma unroll
        for (int reg=0; reg<4; reg++){
            int row = quad*4 + reg;         // C/D: row=quad*4+reg, col=lane&15
            outp[((long)blockIdx.x*16 + row)*HF + o0 + col] = f2b(acc[reg] + bc);
        }
    }
}

// ---------------- K2: fused edge kernel (MFMA), 16 sorted edges/block -----------------
// R10: R8 grid + sorted edges + block-local run-aggregated scatter + batched vector gathers
struct __align__(16) EdgeSmem {
    int   i[16];
    int   jv[16];
    float unit[16][3];
    float attn[16][4];
    ushort_t rbf[16][72];           // row stride 144B
    union {
        ushort_t dkdv[2][16][520];  // row stride 1040B; dead after P4
        float    outb[16*385];      // overlay for P5/P6
    };
    ushort_t msg[16][520];          // row stride 1040B
};

__global__ __launch_bounds__(256, 3) void k_edge(
    const void* __restrict__ r_ij, const void* __restrict__ lng,
    const int* __restrict__ nbrs32, const int* __restrict__ perm,
    const ushort_t* __restrict__ q, const ushort_t* __restrict__ k, const ushort_t* __restrict__ v,
    const void* __restrict__ v_j,
    const ushort_t* __restrict__ WdkT, const ushort_t* __restrict__ WdvT,
    const ushort_t* __restrict__ cb,
    const ushort_t* __restrict__ WdT,
    float* __restrict__ acc_s, float* __restrict__ acc_v)
{
    __shared__ EdgeSmem sm;
    const int t = threadIdx.x;
    const long e0 = (long)blockIdx.x * 16;
    const bool fp32 = is_fp32(lng);
    const int lane = t & 63, w = t >> 6;
    const int col = lane & 15, quad = lane >> 4;

    // ---- Stage A (no internal barrier): per-thread edge eA = t>>4, g = t&15 ----
    const int eA = t >> 4, g = t & 15;
    const int h = g >> 2, sub = g & 3;
    const long ep = perm[e0 + eA];                 // 16 threads share -> L1
    const int iA = nbrs32[2*ep];
    const int jA = nbrs32[2*ep+1];
    {
        float rx = ld_f(r_ij, ep*3+0, fp32);
        float ry = ld_f(r_ij, ep*3+1, fp32);
        float rz = ld_f(r_ij, ep*3+2, fp32);
        float d = sqrtf(rx*rx + ry*ry + rz*rz + 3e-15f);
        float inv = 1.f/d;
        if (g == 0){
            sm.i[eA] = iA; sm.jv[eA] = jA;
            sm.unit[eA][0] = rx*inv; sm.unit[eA][1] = ry*inv; sm.unit[eA][2] = rz*inv;
        }
        // rbf: this thread covers m = g*4 .. g*4+3 (zero-pad to 64)
        const float WIDTH = 5.f/49.f;
        const float GAMMA = 0.5f/(WIDTH*WIDTH);
        short4v rv;
        #pragma unroll
        for (int u=0; u<4; u++){
            int m = g*4 + u;
            float val = 0.f;
            if (m < NRBF){ float dm = d - (float)m*WIDTH; val = __expf(-GAMMA*dm*dm); }
            rv[u] = (short)f2b(val);
        }
        *reinterpret_cast<short4v*>(&sm.rbf[eA][g*4]) = rv;
    }
    // prefetch q[iA], k[jA] fragments for P3 (f-range: h*128 + sub*32, 32 elems)
    short8 qf[4], kf[4];
    {
        const ushort_t* qp = q + (long)iA*HF + h*128 + sub*32;
        const ushort_t* kp = k + (long)jA*HF + h*128 + sub*32;
        #pragma unroll
        for (int r=0; r<4; r++){
            qf[r] = *reinterpret_cast<const short8*>(qp + r*8);
            kf[r] = *reinterpret_cast<const short8*>(kp + r*8);
        }
    }
    __syncthreads();

    // ---- P2: dk/dv = silu(rbf @ Wdk/Wdv + b) via MFMA (K=64 -> 2 steps) ----
    {
        short8 a0 = *reinterpret_cast<const short8*>(&sm.rbf[col][quad*8]);
        short8 a1 = *reinterpret_cast<const short8*>(&sm.rbf[col][32 + quad*8]);
        for (int ii=0; ii<16; ii++){
            int nt = w + ii*4;
            int mat = nt >> 5, o0 = (nt & 31) << 4;
            const ushort_t* WT  = mat ? WdvT : WdkT;
            const ushort_t* bia = cb + 1792 + mat*512;
            floatx4 acc = {0.f,0.f,0.f,0.f};
            short8 b0 = *reinterpret_cast<const short8*>(WT + (o0+col)*64 + quad*8);
            acc = __builtin_amdgcn_mfma_f32_16x16x32_bf16(a0, b0, acc, 0, 0, 0);
            short8 b1 = *reinterpret_cast<const short8*>(WT + (o0+col)*64 + 32 + quad*8);
            acc = __builtin_amdgcn_mfma_f32_16x16x32_bf16(a1, b1, acc, 0, 0, 0);
            float bc = b2f(bia[o0+col]);
            #pragma unroll
            for (int reg=0; reg<4; reg++){
                int row = quad*4 + reg;
                sm.dkdv[mat][row][o0+col] = f2b(silu_f(acc[reg] + bc));
            }
        }
    }
    __syncthreads();

    // ---- P3: attn + v prefetch. Thread (eA, g): 32 products, reduce over 4 lanes ----
    short8 vf[4];
    {
        const ushort_t* vp = v + (long)jA*HF + g*32;   // prefetch for P4
        #pragma unroll
        for (int r=0; r<4; r++) vf[r] = *reinterpret_cast<const short8*>(vp + r*8);

        const ushort_t* dkp = &sm.dkdv[0][eA][h*128 + sub*32];
        float p = 0.f;
        #pragma unroll
        for (int r=0; r<4; r++){
            short8 d8 = *reinterpret_cast<const short8*>(dkp + r*8);
            #pragma unroll
            for (int u=0; u<8; u++)
                p += b2f((unsigned short)qf[r][u]) * b2f((unsigned short)kf[r][u]) * b2f((unsigned short)d8[u]);
        }
        p += __shfl_xor(p, 1);
        p += __shfl_xor(p, 2);
        if (sub == 0) sm.attn[eA][h] = silu_f(p);
    }
    __syncthreads();

    // ---- P4: msg[eA][g*32..+32] = v * dv * attn ----
    {
        float at = sm.attn[eA][g >> 2];
        const ushort_t* dvp = &sm.dkdv[1][eA][g*32];
        #pragma unroll
        for (int r=0; r<4; r++){
            short8 d8 = *reinterpret_cast<const short8*>(dvp + r*8);
            short8 o8;
            #pragma unroll
            for (int u=0; u<8; u++)
                o8[u] = (short)f2b(b2f((unsigned short)vf[r][u]) * b2f((unsigned short)d8[u]) * at);
            *reinterpret_cast<short8*>(&sm.msg[eA][g*32 + r*8]) = o8;
        }
    }
    __syncthreads();

    // ---- P5: out = msg(16x512) @ Wd(512x384) + bd via MFMA; overlays dk/dv ----
    {
        floatx4 acc[6];
        #pragma unroll
        for (int ii=0; ii<6; ii++) acc[ii] = (floatx4){0.f,0.f,0.f,0.f};
        for (int ks=0; ks<16; ks++){
            short8 a = *reinterpret_cast<const short8*>(&sm.msg[col][ks*32 + quad*8]);
            #pragma unroll
            for (int ii=0; ii<6; ii++){
                int o0 = (w + ii*4) << 4;
                short8 b = *reinterpret_cast<const short8*>(WdT + (o0+col)*HF + ks*32 + quad*8);
                acc[ii] = __builtin_amdgcn_mfma_f32_16x16x32_bf16(a, b, acc[ii], 0, 0, 0);
            }
        }
        #pragma unroll
        for (int ii=0; ii<6; ii++){
            int o0 = (w + ii*4) << 4;
            float bc = b2f(cb[2816 + o0 + col]);
            #pragma unroll
            for (int reg=0; reg<4; reg++){
                int row = quad*4 + reg;
                sm.outb[row*385 + o0 + col] = acc[ii][reg] + bc;
            }
        }
    }
    __syncthreads();

    // ---- P6: run-aggregated scatter (sorted by i); two 8-edge halves, 256 threads ----
    {
        const int f = t & 127, half = t >> 7;
        int   cur_i = -1;
        float as = 0.f, av0 = 0.f, av1 = 0.f, av2 = 0.f;
        for (int e = half*8; e < half*8 + 8; e++){
            int ie = sm.i[e];
            if (ie != cur_i){                    // uniform across the 128-thread half
                if (cur_i >= 0){
                    atomicAdd(&acc_s[(long)cur_i*FEAT + f], as);
                    float* ap = acc_v + ((long)cur_i*FEAT + f)*3;
                    atomicAdd(ap+0, av0); atomicAdd(ap+1, av1); atomicAdd(ap+2, av2);
                }
                cur_i = ie; as = 0.f; av0 = 0.f; av1 = 0.f; av2 = 0.f;
            }
            float o0v = sm.outb[e*385 + f];
            float o1v = sm.outb[e*385 + 128 + f];
            float o2v = sm.outb[e*385 + 256 + f];
            long base = ((long)sm.jv[e]*FEAT + f)*3;
            float vj0 = ld_f(v_j, base+0, fp32);
            float vj1 = ld_f(v_j, base+1, fp32);
            float vj2 = ld_f(v_j, base+2, fp32);
            as  += o1v;
            av0 += o2v*sm.unit[e][0] + o0v*vj0;
            av1 += o2v*sm.unit[e][1] + o0v*vj1;
            av2 += o2v*sm.unit[e][2] + o0v*vj2;
        }
        if (cur_i >= 0){
            atomicAdd(&acc_s[(long)cur_i*FEAT + f], as);
            float* ap = acc_v + ((long)cur_i*FEAT + f)*3;
            atomicAdd(ap+0, av0); atomicAdd(ap+1, av1); atomicAdd(ap+2, av2);
        }
    }
}

// ---------------- fp32 accumulators -> fp32 output ----------------
__global__ __launch_bounds__(256) void k_out(const float* __restrict__ acc, float* __restrict__ out){
    int idx = blockIdx.x*256 + threadIdx.x;
    out[idx] = acc[idx];
}

extern "C" void kernel_launch(void* const* d_in, const int* in_sizes, int n_in,
                              void* d_out, int out_size, void* d_ws, size_t ws_size,
                              hipStream_t stream)
{
    const void* s_j  = d_in[0];
    const void* v_j  = d_in[1];
    const void* r_ij = d_in[2];
    const unsigned int* nbrs_raw = (const unsigned int*)d_in[3];
    const void* ln_g = d_in[4];
    const void* ln_b = d_in[5];
    const void* Wq = d_in[6];   const void* bq  = d_in[7];
    const void* Wk = d_in[8];   const void* bk  = d_in[9];
    const void* Wv = d_in[10];  const void* bv  = d_in[11];
    const void* Wdk= d_in[12];  const void* bdk = d_in[13];
    const void* Wdv= d_in[14];  const void* bdv = d_in[15];
    const void* Wd = d_in[16];  const void* bd  = d_in[17];

    // ws layout (bytes) — identical to R8/R9 (proven size):
    const size_t NEED = 43883904;
    if (ws_size < NEED){
        k_sentinel<<<20000, 256, 0, stream>>>((float*)d_out);
        return;
    }

    char* ws = (char*)d_ws;
    float*    acc  = (float*)(ws);
    ushort_t* kk   = (ushort_t*)(ws + 20480000);
    ushort_t* vv   = (ushort_t*)(ws + 30720000);
    ushort_t* WqT  = (ushort_t*)(ws + 40960000);
    ushort_t* WkT  = (ushort_t*)(ws + 41091072);
    ushort_t* WvT  = (ushort_t*)(ws + 41222144);
    ushort_t* WdkT = (ushort_t*)(ws + 41353216);
    ushort_t* WdvT = (ushort_t*)(ws + 41418752);
    ushort_t* WdT  = (ushort_t*)(ws + 41484288);
    int*      nb32 = (int*)(ws + 41877504);
    ushort_t* cb   = (ushort_t*)(ws + 43877504);

    // d_out (20.48 MB fp32) doubles as scratch until k_out:
    char* dob = (char*)d_out;
    ushort_t* q    = (ushort_t*)dob;                // [0, 10.24MB) bf16 q staging
    int*      perm = (int*)(dob + 10240000);        // 1 MB
    int*      cnt  = (int*)(dob + 11240000);
    int*      curs = (int*)(dob + 11280000);

    hipMemsetAsync(acc, 0, 20480000, stream);
    hipMemsetAsync(cnt, 0, NNODE*sizeof(int), stream);
    k_nbrs <<<1954, 256, 0, stream>>>(nbrs_raw, nb32);
    k_count<<<977, 256, 0, stream>>>(nb32, cnt);
    k_scan <<<1, 256, 0, stream>>>(cnt, curs);
    k_place<<<977, 256, 0, stream>>>(nb32, curs, perm);
    k_conv <<<1, 256, 0, stream>>>(ln_g, ln_b, bq, bk, bv, bdk, bdv, bd, cb);
    k_prep <<<1792, 256, 0, stream>>>(Wq,Wk,Wv,Wdk,Wdv,Wd, ln_g, WqT,WkT,WvT,WdkT,WdvT,WdT);
    k_qkv2 <<<625, 256, 0, stream>>>(s_j, ln_g, cb, WqT, WkT, WvT, q, kk, vv);
    k_edge <<<15625, 256, 0, stream>>>(r_ij, ln_g, nb32, perm, q, kk, vv, v_j,
                                       WdkT, WdvT, cb, WdT,
                                       acc, acc + 1280000);
    k_out  <<<20000, 256, 0, stream>>>(acc, (float*)d_out);
}

// Round 11
// 1190.132 us; speedup vs baseline: 2.1332x; 1.0451x over previous
//
#include <hip/hip_runtime.h>
#include <hip/hip_bf16.h>

typedef unsigned short ushort_t;
typedef short short8 __attribute__((ext_vector_type(8)));
typedef short short4v __attribute__((ext_vector_type(4)));
typedef float floatx4 __attribute__((ext_vector_type(4)));

#define FEAT 128
#define HF   512
#define NRBF 50
#define NNODE 10000
#define NEDGE 250000

__device__ __forceinline__ float b2f(unsigned int b){
    unsigned int u = (b & 0xffffu) << 16;
    float f; __builtin_memcpy(&f, &u, 4); return f;
}
__device__ __forceinline__ unsigned short f2b(float f){
    __hip_bfloat16 h = __float2bfloat16(f);
    unsigned short u; __builtin_memcpy(&u, &h, 2); return u;
}
__device__ __forceinline__ float silu_f(float x){ return x / (1.f + __expf(-x)); }

// fp32 inputs iff low 16 bits of ln_gamma[0] are zero (R4/R7: fp32 confirmed on HW)
__device__ __forceinline__ bool is_fp32(const void* lng){
    return ((((const unsigned int*)lng)[0]) & 0xffffu) == 0u;
}
__device__ __forceinline__ float ld_f(const void* p, long idx, bool fp32){
    return fp32 ? ((const float*)p)[idx] : b2f(((const ushort_t*)p)[idx]);
}
__device__ __forceinline__ ushort_t ld_bf(const void* p, long idx, bool fp32){
    return fp32 ? f2b(((const float*)p)[idx]) : ((const ushort_t*)p)[idx];
}

// ---------------- sentinel (ws too small; should never fire) --------------------------
__global__ __launch_bounds__(256) void k_sentinel(float* __restrict__ out){
    int x = blockIdx.x*256 + threadIdx.x;
    if (x < NNODE*FEAT*4) out[x] = 1.0f;
}

// ---------------- normalize nbrs (int32 or int64) -> clamped int32 --------------------
__global__ __launch_bounds__(256) void k_nbrs(const unsigned int* __restrict__ raw, int* __restrict__ out){
    int x = blockIdx.x*256 + threadIdx.x;
    if (x >= 2*NEDGE) return;
    unsigned int m = raw[1]|raw[3]|raw[5]|raw[7]|raw[9]|raw[11]|raw[13]|raw[15];
    int v = (m == 0u) ? (int)raw[2*x] : (int)raw[x];
    out[x] = ((unsigned)v < (unsigned)NNODE) ? v : 0;
}

// ---------------- counting sort of edges by destination i (validated R9/R10) ----------
__global__ __launch_bounds__(256) void k_count(const int* __restrict__ nb32, int* __restrict__ cnt){
    int x = blockIdx.x*256 + threadIdx.x;
    if (x >= NEDGE) return;
    atomicAdd(&cnt[nb32[2*x]], 1);
}
__global__ __launch_bounds__(256) void k_scan(const int* __restrict__ cnt, int* __restrict__ cursor){
    __shared__ int part[256];
    __shared__ int base[256];
    const int t = threadIdx.x;
    const int start = t*40;                 // 256*40 = 10240 >= 10000
    int s = 0;
    for (int u=0; u<40; u++){ int idx = start+u; if (idx < NNODE) s += cnt[idx]; }
    part[t] = s;
    __syncthreads();
    if (t == 0){
        int run = 0;
        for (int u=0; u<256; u++){ base[u] = run; run += part[u]; }
    }
    __syncthreads();
    int run = base[t];
    for (int u=0; u<40; u++){
        int idx = start+u;
        if (idx < NNODE){ cursor[idx] = run; run += cnt[idx]; }
    }
}
__global__ __launch_bounds__(256) void k_place(const int* __restrict__ nb32,
                                               int* __restrict__ cursor, int* __restrict__ perm){
    int x = blockIdx.x*256 + threadIdx.x;
    if (x >= NEDGE) return;
    int i = nb32[2*x];
    int pos = atomicAdd(&cursor[i], 1);
    perm[pos] = x;
}

// ---------------- canonicalize ln/biases -> bf16 block --------------------------------
// cb (ushort): ln_g@0(128) ln_b@128(128) bq@256 bk@768 bv@1280 bdk@1792 bdv@2304 bd@2816(384)
__global__ __launch_bounds__(256) void k_conv(
    const void* ln_g, const void* ln_b, const void* bq, const void* bk, const void* bv,
    const void* bdk, const void* bdv, const void* bd, ushort_t* __restrict__ cb)
{
    const int t = threadIdx.x;
    const bool fp32 = is_fp32(ln_g);
    const void* srcs[8] = {ln_g, ln_b, bq, bk, bv, bdk, bdv, bd};
    const int offs[9] = {0,128,256,768,1280,1792,2304,2816,3200};
    for (int s=0; s<8; s++){
        int cnt = offs[s+1]-offs[s];
        for (int x=t; x<cnt; x+=256) cb[offs[s]+x] = ld_bf(srcs[s], x, fp32);
    }
}

// ---------------- v_j -> bf16 copy (halves the largest gather stream) -----------------
__global__ __launch_bounds__(256) void k_vconv(const void* __restrict__ v_j,
                                               const void* __restrict__ lng,
                                               ushort_t* __restrict__ vjb){
    int x = blockIdx.x*256 + threadIdx.x;
    if (x >= NNODE*FEAT*3) return;
    vjb[x] = ld_bf(v_j, x, is_fp32(lng));
}

// ---------------- weight transposes into B-fragment layouts ---------------------------
// WqT/WkT/WvT: [512][128]; WdkT/WdvT: [512][64] (k zero-padded 50..63); WdT: [384][512]
__global__ __launch_bounds__(256) void k_prep(
    const void* __restrict__ Wq, const void* __restrict__ Wk, const void* __restrict__ Wv,
    const void* __restrict__ Wdk, const void* __restrict__ Wdv, const void* __restrict__ Wd,
    const void* __restrict__ lng,
    ushort_t* __restrict__ WqT, ushort_t* __restrict__ WkT, ushort_t* __restrict__ WvT,
    ushort_t* __restrict__ WdkT, ushort_t* __restrict__ WdvT, ushort_t* __restrict__ WdT)
{
    const bool fp32 = is_fp32(lng);
    int idx = blockIdx.x*256 + threadIdx.x;
    if (idx < 3*65536){
        int mat = idx >> 16; int o = idx & 65535;
        int c = o >> 7, r = o & 127;
        const void* src = (mat==0)?Wq:((mat==1)?Wk:Wv);
        ushort_t* dst = (mat==0)?WqT:((mat==1)?WkT:WvT);
        dst[o] = ld_bf(src, r*HF + c, fp32);
    } else if (idx < 3*65536 + 2*32768){
        int o2 = idx - 3*65536; int mat = o2 >> 15; int o = o2 & 32767;
        int c = o >> 6, kk = o & 63;
        const void* src = mat ? Wdv : Wdk;
        ushort_t* dst = mat ? WdvT : WdkT;
        dst[o] = (kk < NRBF) ? ld_bf(src, kk*HF + c, fp32) : (ushort_t)0;
    } else {
        int o = idx - (3*65536 + 2*32768);
        int c = o >> 9, kk = o & 511;
        WdT[o] = ld_bf(Wd, kk*384 + c, fp32);
    }
}

// ---------------- K1: LayerNorm + QKV projections (MFMA, 16 nodes/block) --------------
__global__ __launch_bounds__(256) void k_qkv2(
    const void* __restrict__ s_j, const void* __restrict__ lng, const ushort_t* __restrict__ cb,
    const ushort_t* __restrict__ WqT, const ushort_t* __restrict__ WkT, const ushort_t* __restrict__ WvT,
    ushort_t* __restrict__ q, ushort_t* __restrict__ k, ushort_t* __restrict__ v)
{
    __shared__ __align__(16) ushort_t xlds[16][136];   // row stride 272B = 17*16
    const int t = threadIdx.x;
    const int n = t >> 4, g = t & 15;
    const long node = (long)blockIdx.x*16 + n;
    const bool fp32 = is_fp32(lng);

    float xs[8];
    if (fp32){
        const float* sf = (const float*)s_j + node*FEAT + g*8;
        #pragma unroll
        for (int i=0;i<8;i++) xs[i] = sf[i];
    } else {
        short8 sv = *reinterpret_cast<const short8*>((const ushort_t*)s_j + node*FEAT + g*8);
        #pragma unroll
        for (int i=0;i<8;i++) xs[i] = b2f((unsigned short)sv[i]);
    }
    float sum = 0.f, ss = 0.f;
    #pragma unroll
    for (int i=0;i<8;i++){ sum += xs[i]; ss += xs[i]*xs[i]; }
    #pragma unroll
    for (int off=8; off; off>>=1){ sum += __shfl_xor(sum, off, 16); ss += __shfl_xor(ss, off, 16); }
    float mu = sum * (1.f/FEAT);
    float var = ss * (1.f/FEAT) - mu*mu;       // population var (jnp.var)
    float sc = rsqrtf(var + 1e-5f);
    short8 gv  = *reinterpret_cast<const short8*>(cb + g*8);
    short8 bv2 = *reinterpret_cast<const short8*>(cb + 128 + g*8);
    short8 xv;
    #pragma unroll
    for (int i=0;i<8;i++){
        float val = (xs[i]-mu)*sc*b2f((unsigned short)gv[i]) + b2f((unsigned short)bv2[i]);
        xv[i] = (short)f2b(val);
    }
    *reinterpret_cast<short8*>(&xlds[n][g*8]) = xv;
    __syncthreads();

    const int lane = t & 63, w = t >> 6;
    const int col = lane & 15, quad = lane >> 4;
    short8 a[4];
    #pragma unroll
    for (int ks=0; ks<4; ks++)
        a[ks] = *reinterpret_cast<const short8*>(&xlds[col][ks*32 + quad*8]);

    for (int ii=0; ii<24; ii++){
        int nt = w + ii*4;
        int mat = nt >> 5, o0 = (nt & 31) << 4;
        const ushort_t* WT  = (mat==0)?WqT:((mat==1)?WkT:WvT);
        const ushort_t* bia = cb + 256 + mat*512;
        ushort_t* outp      = (mat==0)?q:((mat==1)?k:v);
        floatx4 acc = {0.f,0.f,0.f,0.f};
        #pragma unroll
        for (int ks=0; ks<4; ks++){
            short8 b = *reinterpret_cast<const short8*>(WT + (o0+col)*FEAT + ks*32 + quad*8);
            acc = __builtin_amdgcn_mfma_f32_16x16x32_bf16(a[ks], b, acc, 0, 0, 0);
        }
        float bc = b2f(bia[o0+col]);
        #pragma unroll
        for (int reg=0; reg<4; reg++){
            int row = quad*4 + reg;         // C/D: row=quad*4+reg, col=lane&15
            outp[((long)blockIdx.x*16 + row)*HF + o0 + col] = f2b(acc[reg] + bc);
        }
    }
}

// ---------------- K2: fused edge kernel (MFMA), 16 sorted edges/block -----------------
// R11: LDS 36.2KB (msg in-place over dv; outb overlay gated by barrier) -> 4 blocks/CU;
//      bf16 v_j; XCD swizzle; atomics straight into d_out.
struct __align__(16) EdgeSmem {
    int   i[16];
    int   jv[16];
    float unit[16][3];
    float attn[16][4];
    ushort_t rbf[16][72];           // row stride 144B
    union {
        ushort_t dkdv[2][16][520];  // [0]=dk (dead after P3), [1]=dv -> msg in place (P4)
        float    outb[16*385];      // written in P5 AFTER barrier (msg dead)
    };
};

__global__ __launch_bounds__(256, 4) void k_edge(
    const void* __restrict__ r_ij, const void* __restrict__ lng,
    const int* __restrict__ nbrs32, const int* __restrict__ perm,
    const ushort_t* __restrict__ q, const ushort_t* __restrict__ k, const ushort_t* __restrict__ v,
    const ushort_t* __restrict__ vjb,
    const ushort_t* __restrict__ WdkT, const ushort_t* __restrict__ WdvT,
    const ushort_t* __restrict__ cb,
    const ushort_t* __restrict__ WdT,
    float* __restrict__ acc_s, float* __restrict__ acc_v)
{
    __shared__ EdgeSmem sm;
    const int t = threadIdx.x;
    // XCD-aware swizzle: blocks with equal (blockIdx%8) presumably share an XCD;
    // give each group a contiguous span of sorted-edge chunks for q-run L2 locality.
    const long chunk = (long)(blockIdx.x & 7) * 1954 + (blockIdx.x >> 3);
    if (chunk >= NEDGE/16) return;
    const long e0 = chunk * 16;
    const bool fp32 = is_fp32(lng);
    const int lane = t & 63, w = t >> 6;
    const int col = lane & 15, quad = lane >> 4;

    // ---- Stage A: per-thread edge eA = t>>4, g = t&15 (no internal barrier) ----
    const int eA = t >> 4, g = t & 15;
    const int h = g >> 2, sub = g & 3;
    const long ep = perm[e0 + eA];
    const int iA = nbrs32[2*ep];
    const int jA = nbrs32[2*ep+1];
    {
        float rx = ld_f(r_ij, ep*3+0, fp32);
        float ry = ld_f(r_ij, ep*3+1, fp32);
        float rz = ld_f(r_ij, ep*3+2, fp32);
        float d = sqrtf(rx*rx + ry*ry + rz*rz + 3e-15f);
        float inv = 1.f/d;
        if (g == 0){
            sm.i[eA] = iA; sm.jv[eA] = jA;
            sm.unit[eA][0] = rx*inv; sm.unit[eA][1] = ry*inv; sm.unit[eA][2] = rz*inv;
        }
        const float WIDTH = 5.f/49.f;
        const float GAMMA = 0.5f/(WIDTH*WIDTH);
        short4v rv;
        #pragma unroll
        for (int u=0; u<4; u++){
            int m = g*4 + u;
            float val = 0.f;
            if (m < NRBF){ float dm = d - (float)m*WIDTH; val = __expf(-GAMMA*dm*dm); }
            rv[u] = (short)f2b(val);
        }
        *reinterpret_cast<short4v*>(&sm.rbf[eA][g*4]) = rv;
    }
    // prefetch q[iA], k[jA] fragments for P3 (f-range: h*128 + sub*32)
    short8 qf[4], kf[4];
    {
        const ushort_t* qp = q + (long)iA*HF + h*128 + sub*32;
        const ushort_t* kp = k + (long)jA*HF + h*128 + sub*32;
        #pragma unroll
        for (int r=0; r<4; r++){
            qf[r] = *reinterpret_cast<const short8*>(qp + r*8);
            kf[r] = *reinterpret_cast<const short8*>(kp + r*8);
        }
    }
    __syncthreads();

    // ---- P2: dk/dv = silu(rbf @ Wdk/Wdv + b) via MFMA (K=64 -> 2 steps) ----
    {
        short8 a0 = *reinterpret_cast<const short8*>(&sm.rbf[col][quad*8]);
        short8 a1 = *reinterpret_cast<const short8*>(&sm.rbf[col][32 + quad*8]);
        for (int ii=0; ii<16; ii++){
            int nt = w + ii*4;
            int mat = nt >> 5, o0 = (nt & 31) << 4;
            const ushort_t* WT  = mat ? WdvT : WdkT;
            const ushort_t* bia = cb + 1792 + mat*512;
            floatx4 acc = {0.f,0.f,0.f,0.f};
            short8 b0 = *reinterpret_cast<const short8*>(WT + (o0+col)*64 + quad*8);
            acc = __builtin_amdgcn_mfma_f32_16x16x32_bf16(a0, b0, acc, 0, 0, 0);
            short8 b1 = *reinterpret_cast<const short8*>(WT + (o0+col)*64 + 32 + quad*8);
            acc = __builtin_amdgcn_mfma_f32_16x16x32_bf16(a1, b1, acc, 0, 0, 0);
            float bc = b2f(bia[o0+col]);
            #pragma unroll
            for (int reg=0; reg<4; reg++){
                int row = quad*4 + reg;
                sm.dkdv[mat][row][o0+col] = f2b(silu_f(acc[reg] + bc));
            }
        }
    }
    __syncthreads();

    // ---- P3: attn + v prefetch. Thread (eA, g): 32 products, reduce over 4 lanes ----
    short8 vf[4];
    {
        const ushort_t* vp = v + (long)jA*HF + g*32;   // prefetch for P4
        #pragma unroll
        for (int r=0; r<4; r++) vf[r] = *reinterpret_cast<const short8*>(vp + r*8);

        const ushort_t* dkp = &sm.dkdv[0][eA][h*128 + sub*32];
        float p = 0.f;
        #pragma unroll
        for (int r=0; r<4; r++){
            short8 d8 = *reinterpret_cast<const short8*>(dkp + r*8);
            #pragma unroll
            for (int u=0; u<8; u++)
                p += b2f((unsigned short)qf[r][u]) * b2f((unsigned short)kf[r][u]) * b2f((unsigned short)d8[u]);
        }
        p += __shfl_xor(p, 1);
        p += __shfl_xor(p, 2);
        if (sub == 0) sm.attn[eA][h] = silu_f(p);
    }
    __syncthreads();

    // ---- P4: msg in place over dv: dkdv[1][eA][g*32..+32] = v * dv * attn ----
    {
        float at = sm.attn[eA][g >> 2];
        ushort_t* dvp = &sm.dkdv[1][eA][g*32];
        #pragma unroll
        for (int r=0; r<4; r++){
            short8 d8 = *reinterpret_cast<const short8*>(dvp + r*8);
            short8 o8;
            #pragma unroll
            for (int u=0; u<8; u++)
                o8[u] = (short)f2b(b2f((unsigned short)vf[r][u]) * b2f((unsigned short)d8[u]) * at);
            *reinterpret_cast<short8*>(dvp + r*8) = o8;
        }
    }
    __syncthreads();

    // ---- P5: out = msg(16x512) @ Wd(512x384) + bd via MFMA ----
    {
        floatx4 acc[6];
        #pragma unroll
        for (int ii=0; ii<6; ii++) acc[ii] = (floatx4){0.f,0.f,0.f,0.f};
        for (int ks=0; ks<16; ks++){
            short8 a = *reinterpret_cast<const short8*>(&sm.dkdv[1][col][ks*32 + quad*8]);
            #pragma unroll
            for (int ii=0; ii<6; ii++){
                int o0 = (w + ii*4) << 4;
                short8 b = *reinterpret_cast<const short8*>(WdT + (o0+col)*HF + ks*32 + quad*8);
                acc[ii] = __builtin_amdgcn_mfma_f32_16x16x32_bf16(a, b, acc[ii], 0, 0, 0);
            }
        }
        __syncthreads();       // all msg reads done -> safe to overlay outb on dk/dv
        #pragma unroll
        for (int ii=0; ii<6; ii++){
            int o0 = (w + ii*4) << 4;
            float bc = b2f(cb[2816 + o0 + col]);
            #pragma unroll
            for (int reg=0; reg<4; reg++){
                int row = quad*4 + reg;
                sm.outb[row*385 + o0 + col] = acc[ii][reg] + bc;
            }
        }
    }
    __syncthreads();

    // ---- P6: run-aggregated scatter (sorted by i); vjb loads pre-issued ----
    {
        const int f = t & 127, half = t >> 7;
        float vjx[8][3];
        #pragma unroll
        for (int u=0; u<8; u++){
            const ushort_t* vp = vjb + (long)sm.jv[half*8+u]*384 + 3*f;
            vjx[u][0] = b2f(vp[0]); vjx[u][1] = b2f(vp[1]); vjx[u][2] = b2f(vp[2]);
        }
        int   cur_i = -1;
        float as = 0.f, av0 = 0.f, av1 = 0.f, av2 = 0.f;
        #pragma unroll
        for (int u=0; u<8; u++){
            int e = half*8 + u;
            int ie = sm.i[e];
            if (ie != cur_i){                    // uniform across the 128-thread half
                if (cur_i >= 0){
                    atomicAdd(&acc_s[(long)cur_i*FEAT + f], as);
                    float* ap = acc_v + ((long)cur_i*FEAT + f)*3;
                    atomicAdd(ap+0, av0); atomicAdd(ap+1, av1); atomicAdd(ap+2, av2);
                }
                cur_i = ie; as = 0.f; av0 = 0.f; av1 = 0.f; av2 = 0.f;
            }
            float o0v = sm.outb[e*385 + f];
            float o1v = sm.outb[e*385 + 128 + f];
            float o2v = sm.outb[e*385 + 256 + f];
            as  += o1v;
            av0 += o2v*sm.unit[e][0] + o0v*vjx[u][0];
            av1 += o2v*sm.unit[e][1] + o0v*vjx[u][1];
            av2 += o2v*sm.unit[e][2] + o0v*vjx[u][2];
        }
        if (cur_i >= 0){
            atomicAdd(&acc_s[(long)cur_i*FEAT + f], as);
            float* ap = acc_v + ((long)cur_i*FEAT + f)*3;
            atomicAdd(ap+0, av0); atomicAdd(ap+1, av1); atomicAdd(ap+2, av2);
        }
    }
}

extern "C" void kernel_launch(void* const* d_in, const int* in_sizes, int n_in,
                              void* d_out, int out_size, void* d_ws, size_t ws_size,
                              hipStream_t stream)
{
    const void* s_j  = d_in[0];
    const void* v_j  = d_in[1];
    const void* r_ij = d_in[2];
    const unsigned int* nbrs_raw = (const unsigned int*)d_in[3];
    const void* ln_g = d_in[4];
    const void* ln_b = d_in[5];
    const void* Wq = d_in[6];   const void* bq  = d_in[7];
    const void* Wk = d_in[8];   const void* bk  = d_in[9];
    const void* Wv = d_in[10];  const void* bv  = d_in[11];
    const void* Wdk= d_in[12];  const void* bdk = d_in[13];
    const void* Wdv= d_in[14];  const void* bdv = d_in[15];
    const void* Wd = d_in[16];  const void* bd  = d_in[17];

    // ws layout (bytes) — same NEED as R8-R10 (proven):
    //   [0,20.48M): scratch pool: q@0 (10.24M) | vjb@10,240,000 (7.68M) | perm@17,920,000 (1M)
    //               cnt@18,920,000 (40K) | curs@18,960,000 (40K)
    //   kk 20,480,000 | vv 30,720,000 | WqT 40,960,000 WkT WvT | WdkT 41,353,216 WdvT
    //   WdT 41,484,288 | nbrs32 41,877,504 | cb 43,877,504 => NEED 43,883,904
    const size_t NEED = 43883904;
    if (ws_size < NEED){
        k_sentinel<<<20000, 256, 0, stream>>>((float*)d_out);
        return;
    }

    char* ws = (char*)d_ws;
    ushort_t* q    = (ushort_t*)(ws);
    ushort_t* vjb  = (ushort_t*)(ws + 10240000);
    int*      perm = (int*)(ws + 17920000);
    int*      cnt  = (int*)(ws + 18920000);
    int*      curs = (int*)(ws + 18960000);
    ushort_t* kk   = (ushort_t*)(ws + 20480000);
    ushort_t* vv   = (ushort_t*)(ws + 30720000);
    ushort_t* WqT  = (ushort_t*)(ws + 40960000);
    ushort_t* WkT  = (ushort_t*)(ws + 41091072);
    ushort_t* WvT  = (ushort_t*)(ws + 41222144);
    ushort_t* WdkT = (ushort_t*)(ws + 41353216);
    ushort_t* WdvT = (ushort_t*)(ws + 41418752);
    ushort_t* WdT  = (ushort_t*)(ws + 41484288);
    int*      nb32 = (int*)(ws + 41877504);
    ushort_t* cb   = (ushort_t*)(ws + 43877504);

    // atomics accumulate directly into fp32 d_out (20.48 MB): acc_s | acc_v
    float* acc_s = (float*)d_out;
    float* acc_v = acc_s + 1280000;

    hipMemsetAsync(d_out, 0, 20480000, stream);
    hipMemsetAsync(cnt, 0, NNODE*sizeof(int), stream);
    k_nbrs <<<1954, 256, 0, stream>>>(nbrs_raw, nb32);
    k_count<<<977, 256, 0, stream>>>(nb32, cnt);
    k_scan <<<1, 256, 0, stream>>>(cnt, curs);
    k_place<<<977, 256, 0, stream>>>(nb32, curs, perm);
    k_conv <<<1, 256, 0, stream>>>(ln_g, ln_b, bq, bk, bv, bdk, bdv, bd, cb);
    k_vconv<<<15000, 256, 0, stream>>>(v_j, ln_g, vjb);
    k_prep <<<1792, 256, 0, stream>>>(Wq,Wk,Wv,Wdk,Wdv,Wd, ln_g, WqT,WkT,WvT,WdkT,WdvT,WdT);
    k_qkv2 <<<625, 256, 0, stream>>>(s_j, ln_g, cb, WqT, WkT, WvT, q, kk, vv);
    k_edge <<<15632, 256, 0, stream>>>(r_ij, ln_g, nb32, perm, q, kk, vv, vjb,
                                       WdkT, WdvT, cb, WdT,
                                       acc_s, acc_v);
}